// Round 4
// baseline (361.281 us; speedup 1.0000x reference)
//
#include <hip/hip_runtime.h>
#include <math.h>

typedef float f32x4 __attribute__((ext_vector_type(4)));
typedef short s16x8 __attribute__((ext_vector_type(8)));
typedef unsigned int u32;
typedef unsigned short u16;
typedef u16 u16x4 __attribute__((ext_vector_type(4)));

// ---------------- ws layout (float offsets), 54.3 MB total ----------------
static constexpr size_t OFF_XT    = 0;          // bf16 [16,1156,512]
static constexpr size_t OFF_VT    = 4734976;    // bf16 [16,1024,512]
static constexpr size_t OFF_ATTNT = 8929280;    // bf16 [16,512,512]
static constexpr size_t OFF_WATTN = 11026432;   // bf16 [16,256,512]
static constexpr size_t OFF_WA    = 12075008;   // bf16 [512,4608]
static constexpr size_t OFF_RM    = 13254656;   // f32  [512,512]
static constexpr size_t OFF_WWB   = 13516800;   // bf16 [256,512]  end 13,582,336

__device__ __forceinline__ u16 f2bf(float f) {
    u32 u = __float_as_uint(f);
    u32 r = (u + 0x7FFFu + ((u >> 16) & 1u)) >> 16;   // RNE
    return (u16)r;
}

__device__ __forceinline__ void gload_lds16(const void* g, void* l) {
    __builtin_amdgcn_global_load_lds(
        (const u32 __attribute__((address_space(1)))*)(uintptr_t)g,
        (u32 __attribute__((address_space(3)))*)(uintptr_t)l, 16, 0, 0);
}

// ================================================================ PREP (grid-fused)
// [0,1024)      rm = w1 @ w2^T
// [1024,3328)   wA[co][r*512+ci] = bf16(g_w[co][ci][r])   (4 k's per thread)
// [3328,3456)   wwb = bf16(w_w)
// [3456,5888)   xT[b][p][ci] bf16, 34x34 zero-padded channels-last transpose
__global__ __launch_bounds__(256) void prep_kernel(const float* __restrict__ x1,
                                                   const float* __restrict__ x2,
                                                   const float* __restrict__ gw,
                                                   const float* __restrict__ ww,
                                                   const float* __restrict__ w1,
                                                   const float* __restrict__ w2,
                                                   float* __restrict__ rm,
                                                   u16* __restrict__ wA,
                                                   u16* __restrict__ wwb,
                                                   u16* __restrict__ xT) {
    __shared__ u16 ptile[64 * 72];
    const int t = threadIdx.x;
    const int bid = blockIdx.x;

    if (bid < 1024) {                       // ---- rm
        int idx = bid * 256 + t;
        int c = idx >> 9, d = idx & 511;
        float s = 0.f;
#pragma unroll
        for (int k = 0; k < 16; ++k) s = fmaf(w1[c * 16 + k], w2[d * 16 + k], s);
        rm[idx] = s;
    } else if (bid < 3328) {                // ---- wA permuted cast
        int id = (bid - 1024) * 256 + t;    // 589,824 total
        int co = id / 1152;
        int q = id - co * 1152;
        int k0 = q * 4;
        int r = k0 >> 9, ci = k0 & 511;
        const float* g = gw + (size_t)co * 4608 + (size_t)ci * 9 + r;
        u16x4 pk = {f2bf(g[0]), f2bf(g[9]), f2bf(g[18]), f2bf(g[27])};
        *(u16x4*)&wA[(size_t)co * 4608 + k0] = pk;
    } else if (bid < 3456) {                // ---- wwb cast
        int idx = (bid - 3328) * 256 + t;   // 32768 float4 groups
        float4 v = ((const float4*)ww)[idx];
        u16x4 pk = {f2bf(v.x), f2bf(v.y), f2bf(v.z), f2bf(v.w)};
        *(u16x4*)&wwb[(size_t)idx * 4] = pk;
    } else {                                // ---- xpose
        int xid = bid - 3456;               // 19*8*16 = 2432
        int pt = xid % 19;
        int rest = xid / 19;
        int cit = rest & 7, b = rest >> 3;
        int p0 = pt * 64, ci0 = cit * 64;
        const float* src = (ci0 < 256) ? (x1 + ((size_t)(b * 256 + ci0)) * 1024)
                                       : (x2 + ((size_t)(b * 256 + ci0 - 256)) * 1024);
        {
            int ci_i = t >> 2, pj0 = (t & 3) * 16;
#pragma unroll
            for (int s = 0; s < 16; ++s) {
                int p = p0 + pj0 + s;
                float v = 0.f;
                if (p < 1156) {
                    int yy = p / 34, xx = p - yy * 34;
                    if (yy >= 1 && yy <= 32 && xx >= 1 && xx <= 32)
                        v = src[ci_i * 1024 + (yy - 1) * 32 + (xx - 1)];
                }
                ptile[(pj0 + s) * 72 + ci_i] = f2bf(v);
            }
        }
        __syncthreads();
        {
            int p_i = t >> 2, c0 = (t & 3) * 16;
            int p = p0 + p_i;
            if (p < 1156) {
                u16* dst = xT + ((size_t)b * 1156 + p) * 512 + ci0 + c0;
                *(s16x8*)&dst[0] = *(const s16x8*)&ptile[p_i * 72 + c0];
                *(s16x8*)&dst[8] = *(const s16x8*)&ptile[p_i * 72 + c0 + 8];
            }
        }
    }
}

// ================================================================ MEGA
// blocks [0,512):   conv implicit GEMM (bf16 MFMA, 128x128xBK64) -> vT bf16
// blocks [512,768): sim (M=32,N=512,BK=32) + *scale + rm + softmax -> attnT bf16
__global__ __launch_bounds__(256) void mega_kernel(const u16* __restrict__ wA,
                                                   const u16* __restrict__ xT,
                                                   u16* __restrict__ vT,
                                                   const float* __restrict__ x1,
                                                   const float* __restrict__ x2,
                                                   const float* __restrict__ rm,
                                                   u16* __restrict__ attnT) {
    __shared__ __attribute__((aligned(16))) u16 smem[20992];
    const int t = threadIdx.x, w = t >> 6, l = t & 63;

    if (blockIdx.x < 512) {
        // ------------------------------------------------ conv path (unchanged, at plateau)
        u16* As = smem;               // 128 x 64
        u16* Bs = smem + 128 * 64;
        const int cid = blockIdx.x;
        const int b = cid >> 5, mt = (cid >> 3) & 3, nt = cid & 7;
        const int m0 = mt * 128, n0 = nt * 128;
        const u16* xTb = xT + (size_t)b * 1156 * 512;

        int gi[4], pb[4];
        const u16* agp[4];
        u16 *ald[4], *bld[4];
#pragma unroll
        for (int i = 0; i < 4; ++i) {
            int rr = w * 8 + i * 32 + (l >> 3);
            gi[i] = (l & 7) ^ (rr & 7);
            agp[i] = wA + (size_t)(m0 + rr) * 4608 + gi[i] * 8;
            int n = n0 + rr;
            pb[i] = (n >> 5) * 34 + (n & 31);
            ald[i] = &As[(w * 8 + i * 32) * 64];
            bld[i] = &Bs[(w * 8 + i * 32) * 64];
        }

        f32x4 acc[4][4] = {};
        const int wm = (w >> 1) * 64, wn = (w & 1) * 64;

        for (int kt = 0; kt < 72; ++kt) {
            int r = kt >> 3, ci0k = (kt & 7) << 6;
            int rdiv3 = (r * 11) >> 5;
            int poff = rdiv3 * 34 + (r - rdiv3 * 3);
            int aofs = r * 512 + ci0k;
            if (kt) __syncthreads();
#pragma unroll
            for (int i = 0; i < 4; ++i) gload_lds16(agp[i] + aofs, ald[i]);
#pragma unroll
            for (int i = 0; i < 4; ++i)
                gload_lds16(xTb + (size_t)(pb[i] + poff) * 512 + ci0k + gi[i] * 8, bld[i]);
            __syncthreads();

#pragma unroll
            for (int kk = 0; kk < 2; ++kk) {
                int gbase = kk * 4 + (l >> 4);
                s16x8 af[4], bf[4];
#pragma unroll
                for (int i = 0; i < 4; ++i) {
                    int row = wm + i * 16 + (l & 15);
                    af[i] = *(const s16x8*)&As[row * 64 + ((gbase ^ (row & 7)) << 3)];
                }
#pragma unroll
                for (int j = 0; j < 4; ++j) {
                    int row = wn + j * 16 + (l & 15);
                    bf[j] = *(const s16x8*)&Bs[row * 64 + ((gbase ^ (row & 7)) << 3)];
                }
#pragma unroll
                for (int i = 0; i < 4; ++i)
#pragma unroll
                    for (int j = 0; j < 4; ++j)
                        acc[i][j] = __builtin_amdgcn_mfma_f32_16x16x32_bf16(af[i], bf[j], acc[i][j], 0, 0, 0);
            }
        }

        __syncthreads();
        const int col = l & 15, r4 = (l >> 4) * 4;
#pragma unroll
        for (int i = 0; i < 4; ++i)
#pragma unroll
            for (int j = 0; j < 4; ++j) {
                int n_l = wn + j * 16 + col;
                int co_b = wm + i * 16 + r4;
                u16x4 pk = {f2bf(acc[i][j][0]), f2bf(acc[i][j][1]),
                            f2bf(acc[i][j][2]), f2bf(acc[i][j][3])};
                *(u16x4*)&smem[n_l * 128 + (co_b ^ ((n_l & 15) << 3))] = pk;
            }
        __syncthreads();
        u16* vTb = vT + (size_t)b * 1024 * 512;
        {
            int n_l = t >> 1;
#pragma unroll
            for (int rep = 0; rep < 8; ++rep) {
                int c0 = (((t & 1) + rep * 2) << 3);
                s16x8 v = *(const s16x8*)&smem[n_l * 128 + (c0 ^ ((n_l & 15) << 3))];
                *(s16x8*)&vTb[(size_t)(n0 + n_l) * 512 + m0 + c0] = v;
            }
        }
    } else {
        // ------------------------------------------------ sim path (rides in conv's shadow)
        const int q = blockIdx.x - 512;
        const int b = q & 15, m0 = (q >> 4) * 32;   // same-batch blocks share an XCD
        u16* As = smem;            // 32 x 32
        u16* Bs = smem + 1024;     // 512 x 32
        float* scr = (float*)(smem + 20480);        // 256 floats: [0..128) max, [128..256) sum

        f32x4 acc[2][8] = {};
        const int col = l & 15, hi = l >> 4;

        for (int kt = 0; kt < 32; ++kt) {
            const int ko = kt * 32;
            if (kt) __syncthreads();
            // stage B: all 512 channel rows x 32 k, XOR-swizzled 8-u16 chunks
#pragma unroll
            for (int u = 0; u < 8; ++u) {
                int id = t + u * 256;
                int r = id >> 2, p = id & 3, g = p ^ (r & 3);
                const float* src = ((r < 256) ? x1 + ((size_t)(b * 256 + r)) * 1024
                                              : x2 + ((size_t)(b * 256 + r - 256)) * 1024)
                                   + ko + g * 8;
                float4 f0 = *(const float4*)src;
                float4 f1 = *(const float4*)(src + 4);
                s16x8 pk;
                pk[0] = (short)f2bf(f0.x); pk[1] = (short)f2bf(f0.y);
                pk[2] = (short)f2bf(f0.z); pk[3] = (short)f2bf(f0.w);
                pk[4] = (short)f2bf(f1.x); pk[5] = (short)f2bf(f1.y);
                pk[6] = (short)f2bf(f1.z); pk[7] = (short)f2bf(f1.w);
                *(s16x8*)&Bs[r * 32 + p * 8] = pk;
            }
            // stage A: rows m0..m0+31 (waves 0,1)
            if (t < 128) {
                int r = t >> 2, p = t & 3, g = p ^ (r & 3);
                int ch = m0 + r;
                const float* src = ((ch < 256) ? x1 + ((size_t)(b * 256 + ch)) * 1024
                                               : x2 + ((size_t)(b * 256 + ch - 256)) * 1024)
                                   + ko + g * 8;
                float4 f0 = *(const float4*)src;
                float4 f1 = *(const float4*)(src + 4);
                s16x8 pk;
                pk[0] = (short)f2bf(f0.x); pk[1] = (short)f2bf(f0.y);
                pk[2] = (short)f2bf(f0.z); pk[3] = (short)f2bf(f0.w);
                pk[4] = (short)f2bf(f1.x); pk[5] = (short)f2bf(f1.y);
                pk[6] = (short)f2bf(f1.z); pk[7] = (short)f2bf(f1.w);
                *(s16x8*)&As[r * 32 + p * 8] = pk;
            }
            __syncthreads();

            s16x8 af[2], bf[8];
#pragma unroll
            for (int i = 0; i < 2; ++i) {
                int row = i * 16 + col;
                af[i] = *(const s16x8*)&As[row * 32 + ((hi ^ (row & 3)) << 3)];
            }
#pragma unroll
            for (int j = 0; j < 8; ++j) {
                int n = w * 128 + j * 16 + col;
                bf[j] = *(const s16x8*)&Bs[n * 32 + ((hi ^ (n & 3)) << 3)];
            }
#pragma unroll
            for (int i = 0; i < 2; ++i)
#pragma unroll
                for (int j = 0; j < 8; ++j)
                    acc[i][j] = __builtin_amdgcn_mfma_f32_16x16x32_bf16(af[i], bf[j], acc[i][j], 0, 0, 0);
        }

        // ---- epilogue: val = acc*scale + rm; softmax over full row (512) ----
        const float scale = 0.04419417382415922f;
#pragma unroll
        for (int i = 0; i < 2; ++i)
#pragma unroll
            for (int j = 0; j < 8; ++j) {
                int n = w * 128 + j * 16 + col;
#pragma unroll
                for (int reg = 0; reg < 4; ++reg) {
                    int rowg = m0 + i * 16 + hi * 4 + reg;
                    acc[i][j][reg] = acc[i][j][reg] * scale + rm[(size_t)rowg * 512 + n];
                }
            }
        // per-row max: in-reg over j, shfl over cols, cross-wave via scratch
        float mx[2][4];
#pragma unroll
        for (int i = 0; i < 2; ++i)
#pragma unroll
            for (int reg = 0; reg < 4; ++reg) {
                float m = acc[i][0][reg];
#pragma unroll
                for (int j = 1; j < 8; ++j) m = fmaxf(m, acc[i][j][reg]);
                m = fmaxf(m, __shfl_xor(m, 1, 64));
                m = fmaxf(m, __shfl_xor(m, 2, 64));
                m = fmaxf(m, __shfl_xor(m, 4, 64));
                m = fmaxf(m, __shfl_xor(m, 8, 64));
                mx[i][reg] = m;
            }
        if (col == 0) {
#pragma unroll
            for (int i = 0; i < 2; ++i)
#pragma unroll
                for (int reg = 0; reg < 4; ++reg)
                    scr[w * 32 + i * 16 + hi * 4 + reg] = mx[i][reg];
        }
        __syncthreads();
        float sm[2][4];
#pragma unroll
        for (int i = 0; i < 2; ++i)
#pragma unroll
            for (int reg = 0; reg < 4; ++reg) {
                int rowl = i * 16 + hi * 4 + reg;
                float m = fmaxf(fmaxf(scr[rowl], scr[32 + rowl]),
                                fmaxf(scr[64 + rowl], scr[96 + rowl]));
                float s = 0.f;
#pragma unroll
                for (int j = 0; j < 8; ++j) {
                    float e = __expf(acc[i][j][reg] - m);
                    acc[i][j][reg] = e;
                    s += e;
                }
                s += __shfl_xor(s, 1, 64);
                s += __shfl_xor(s, 2, 64);
                s += __shfl_xor(s, 4, 64);
                s += __shfl_xor(s, 8, 64);
                sm[i][reg] = s;
            }
        if (col == 0) {
#pragma unroll
            for (int i = 0; i < 2; ++i)
#pragma unroll
                for (int reg = 0; reg < 4; ++reg)
                    scr[128 + w * 32 + i * 16 + hi * 4 + reg] = sm[i][reg];
        }
        __syncthreads();
        // normalize, cast, write transposed tile [d(512)][c(32)] stride 40
#pragma unroll
        for (int i = 0; i < 2; ++i)
#pragma unroll
            for (int reg = 0; reg < 4; ++reg) {
                int rowl = i * 16 + hi * 4 + reg;
                float tot = scr[128 + rowl] + scr[160 + rowl] + scr[192 + rowl] + scr[224 + rowl];
                float inv = 1.f / tot;
#pragma unroll
                for (int j = 0; j < 8; ++j) acc[i][j][reg] *= inv;
            }
        __syncthreads();   // scratch reads done before tile overwrites smem
#pragma unroll
        for (int i = 0; i < 2; ++i)
#pragma unroll
            for (int j = 0; j < 8; ++j) {
                int d = w * 128 + j * 16 + col;
                int c = i * 16 + hi * 4;
                u16x4 pk = {f2bf(acc[i][j][0]), f2bf(acc[i][j][1]),
                            f2bf(acc[i][j][2]), f2bf(acc[i][j][3])};
                *(u16x4*)&smem[d * 40 + c] = pk;
            }
        __syncthreads();
        // read out: thread -> full 32-wide c-slice of one d row, 64 B coalesced
        {
            u16* aT = attnT + ((size_t)b * 512) * 512 + m0;
#pragma unroll
            for (int rep = 0; rep < 2; ++rep) {
                int d = t + rep * 256;
                u16* dst = aT + (size_t)d * 512;
                s16x8 v0 = *(const s16x8*)&smem[d * 40];
                s16x8 v1 = *(const s16x8*)&smem[d * 40 + 8];
                s16x8 v2 = *(const s16x8*)&smem[d * 40 + 16];
                s16x8 v3 = *(const s16x8*)&smem[d * 40 + 24];
                *(s16x8*)&dst[0] = v0;
                *(s16x8*)&dst[8] = v1;
                *(s16x8*)&dst[16] = v2;
                *(s16x8*)&dst[24] = v3;
            }
        }
    }
}

// ================================================================ generic bf16 MFMA NT GEMM
// C[b][m][n] = sum_k A[b][m][k] * B[b][n][k].  128x128 tile, BK=64.
// MODE 1: bf16 out (wattn); MODE 2: f32 out (final)
template <int MODE>
__global__ __launch_bounds__(256) void gemm_nt(const u16* __restrict__ A, size_t sA,
                                               const u16* __restrict__ B, size_t sB,
                                               void* __restrict__ Cv, size_t sC,
                                               int K, int ldc) {
    __shared__ __attribute__((aligned(16))) u16 As[128 * 64];
    __shared__ __attribute__((aligned(16))) u16 Bs[128 * 64];
    const int b = blockIdx.z, m0 = blockIdx.y * 128, n0 = blockIdx.x * 128;
    const int t = threadIdx.x, w = t >> 6, l = t & 63;
    const u16* Ab = A + (size_t)b * sA;
    const u16* Bb = B + (size_t)b * sB;

    const u16 *agp[4], *bgp[4];
    u16 *ald[4], *bld[4];
#pragma unroll
    for (int i = 0; i < 4; ++i) {
        int rr = w * 8 + i * 32 + (l >> 3);
        int gi = (l & 7) ^ (rr & 7);
        agp[i] = Ab + (size_t)(m0 + rr) * K + gi * 8;
        bgp[i] = Bb + (size_t)(n0 + rr) * K + gi * 8;
        ald[i] = &As[(w * 8 + i * 32) * 64];
        bld[i] = &Bs[(w * 8 + i * 32) * 64];
    }

    f32x4 acc[4][4] = {};
    const int wm = (w >> 1) * 64, wn = (w & 1) * 64;
    const int nkt = K >> 6;
    for (int kt = 0; kt < nkt; ++kt) {
        int ko = kt << 6;
        if (kt) __syncthreads();
#pragma unroll
        for (int i = 0; i < 4; ++i) gload_lds16(agp[i] + ko, ald[i]);
#pragma unroll
        for (int i = 0; i < 4; ++i) gload_lds16(bgp[i] + ko, bld[i]);
        __syncthreads();
#pragma unroll
        for (int kk = 0; kk < 2; ++kk) {
            int gbase = kk * 4 + (l >> 4);
            s16x8 af[4], bf[4];
#pragma unroll
            for (int i = 0; i < 4; ++i) {
                int row = wm + i * 16 + (l & 15);
                af[i] = *(const s16x8*)&As[row * 64 + ((gbase ^ (row & 7)) << 3)];
            }
#pragma unroll
            for (int j = 0; j < 4; ++j) {
                int row = wn + j * 16 + (l & 15);
                bf[j] = *(const s16x8*)&Bs[row * 64 + ((gbase ^ (row & 7)) << 3)];
            }
#pragma unroll
            for (int i = 0; i < 4; ++i)
#pragma unroll
                for (int j = 0; j < 4; ++j)
                    acc[i][j] = __builtin_amdgcn_mfma_f32_16x16x32_bf16(af[i], bf[j], acc[i][j], 0, 0, 0);
        }
    }

    const int col = l & 15, r4 = (l >> 4) * 4;
#pragma unroll
    for (int i = 0; i < 4; ++i)
#pragma unroll
        for (int j = 0; j < 4; ++j)
#pragma unroll
            for (int reg = 0; reg < 4; ++reg) {
                int m = m0 + wm + i * 16 + r4 + reg;
                int n = n0 + wn + j * 16 + col;
                if (MODE == 1) {
                    u16* C = (u16*)Cv + (size_t)b * sC;
                    C[(size_t)m * ldc + n] = f2bf(acc[i][j][reg]);
                } else {
                    float* C = (float*)Cv + (size_t)b * sC;
                    C[(size_t)m * ldc + n] = acc[i][j][reg];
                }
            }
}

// ----------------------------------------------------------------
extern "C" void kernel_launch(void* const* d_in, const int* in_sizes, int n_in,
                              void* d_out, int out_size, void* d_ws, size_t ws_size,
                              hipStream_t stream) {
    (void)in_sizes; (void)n_in; (void)out_size; (void)ws_size;
    const float* x1 = (const float*)d_in[0];
    const float* x2 = (const float*)d_in[1];
    const float* gw = (const float*)d_in[2];
    const float* ww = (const float*)d_in[3];
    const float* w1 = (const float*)d_in[4];
    const float* w2 = (const float*)d_in[5];
    float* out = (float*)d_out;
    float* ws = (float*)d_ws;

    u16* xT    = (u16*)(ws + OFF_XT);
    u16* vT    = (u16*)(ws + OFF_VT);
    u16* attnT = (u16*)(ws + OFF_ATTNT);
    u16* wattn = (u16*)(ws + OFF_WATTN);
    u16* wA    = (u16*)(ws + OFF_WA);
    float* rm  = ws + OFF_RM;
    u16* wwb   = (u16*)(ws + OFF_WWB);

    prep_kernel<<<5888, 256, 0, stream>>>(x1, x2, gw, ww, w1, w2, rm, wA, wwb, xT);
    mega_kernel<<<768, 256, 0, stream>>>(wA, xT, vT, x1, x2, rm, attnT);
    // wattn[b][o][d] = sum_c wwb[o][c] * attnT[b][d][c]  (bf16 out)
    gemm_nt<1><<<dim3(4, 2, 16), 256, 0, stream>>>(
        wwb, 0, attnT, (size_t)512 * 512, wattn, (size_t)256 * 512, 512, 512);
    // out[b][o][n] = sum_d wattn[b][o][d] * vT[b][n][d]  (f32 out)
    gemm_nt<2><<<dim3(8, 2, 16), 256, 0, stream>>>(
        wattn, (size_t)256 * 512, vT, (size_t)1024 * 512, out, (size_t)256 * 1024, 512, 1024);
}

// Round 5
// 264.404 us; speedup vs baseline: 1.3664x; 1.3664x over previous
//
#include <hip/hip_runtime.h>
#include <math.h>

typedef float f32x4 __attribute__((ext_vector_type(4)));
typedef short s16x8 __attribute__((ext_vector_type(8)));
typedef unsigned int u32;
typedef unsigned short u16;
typedef u16 u16x4 __attribute__((ext_vector_type(4)));

// ---------------- ws layout (float offsets), 54.3 MB total ----------------
// vT region is dual-use: xq bf16 [16,512,1024] (prep..sim_fused) then
// vT bf16 [16,1024,512] (conv..out). Same size (4,194,304 floats).
static constexpr size_t OFF_XT    = 0;          // bf16 [16,1156,512]
static constexpr size_t OFF_VT    = 4734976;    // bf16, see above
static constexpr size_t OFF_ATTNT = 8929280;    // bf16 [16,512,512]
static constexpr size_t OFF_WATTN = 11026432;   // bf16 [16,256,512]
static constexpr size_t OFF_WA    = 12075008;   // bf16 [512,4608]
static constexpr size_t OFF_RM    = 13254656;   // f32  [512,512]
static constexpr size_t OFF_WWB   = 13516800;   // bf16 [256,512]  end 13,582,336

__device__ __forceinline__ u16 f2bf(float f) {
    u32 u = __float_as_uint(f);
    u32 r = (u + 0x7FFFu + ((u >> 16) & 1u)) >> 16;   // RNE
    return (u16)r;
}

__device__ __forceinline__ void gload_lds16(const void* g, void* l) {
    __builtin_amdgcn_global_load_lds(
        (const u32 __attribute__((address_space(1)))*)(uintptr_t)g,
        (u32 __attribute__((address_space(3)))*)(uintptr_t)l, 16, 0, 0);
}

// ================================================================ PREP (grid-fused)
// [0,1024)       rm = w1 @ w2^T
// [1024,3328)    wA[co][r*512+ci] = bf16(g_w[co][ci][r])
// [3328,3456)    wwb = bf16(w_w)
// [3456,5888)    xT[b][p][ci] bf16, 34x34 zero-padded channels-last transpose
// [5888,14080)   xq = bf16(concat(x1,x2)) [b,512,1024]
__global__ __launch_bounds__(256) void prep_kernel(const float* __restrict__ x1,
                                                   const float* __restrict__ x2,
                                                   const float* __restrict__ gw,
                                                   const float* __restrict__ ww,
                                                   const float* __restrict__ w1,
                                                   const float* __restrict__ w2,
                                                   float* __restrict__ rm,
                                                   u16* __restrict__ wA,
                                                   u16* __restrict__ wwb,
                                                   u16* __restrict__ xT,
                                                   u16* __restrict__ xq) {
    __shared__ u16 ptile[64 * 72];
    const int t = threadIdx.x;
    const int bid = blockIdx.x;

    if (bid < 1024) {                       // ---- rm
        int idx = bid * 256 + t;
        int c = idx >> 9, d = idx & 511;
        float s = 0.f;
#pragma unroll
        for (int k = 0; k < 16; ++k) s = fmaf(w1[c * 16 + k], w2[d * 16 + k], s);
        rm[idx] = s;
    } else if (bid < 3328) {                // ---- wA permuted cast
        int id = (bid - 1024) * 256 + t;
        int co = id / 1152;
        int q = id - co * 1152;
        int k0 = q * 4;
        int r = k0 >> 9, ci = k0 & 511;
        const float* g = gw + (size_t)co * 4608 + (size_t)ci * 9 + r;
        u16x4 pk = {f2bf(g[0]), f2bf(g[9]), f2bf(g[18]), f2bf(g[27])};
        *(u16x4*)&wA[(size_t)co * 4608 + k0] = pk;
    } else if (bid < 3456) {                // ---- wwb cast
        int idx = (bid - 3328) * 256 + t;
        float4 v = ((const float4*)ww)[idx];
        u16x4 pk = {f2bf(v.x), f2bf(v.y), f2bf(v.z), f2bf(v.w)};
        *(u16x4*)&wwb[(size_t)idx * 4] = pk;
    } else if (bid < 5888) {                // ---- xpose
        int xid = bid - 3456;               // 19*8*16
        int pt = xid % 19;
        int rest = xid / 19;
        int cit = rest & 7, b = rest >> 3;
        int p0 = pt * 64, ci0 = cit * 64;
        const float* src = (ci0 < 256) ? (x1 + ((size_t)(b * 256 + ci0)) * 1024)
                                       : (x2 + ((size_t)(b * 256 + ci0 - 256)) * 1024);
        {
            int ci_i = t >> 2, pj0 = (t & 3) * 16;
#pragma unroll
            for (int s = 0; s < 16; ++s) {
                int p = p0 + pj0 + s;
                float v = 0.f;
                if (p < 1156) {
                    int yy = p / 34, xx = p - yy * 34;
                    if (yy >= 1 && yy <= 32 && xx >= 1 && xx <= 32)
                        v = src[ci_i * 1024 + (yy - 1) * 32 + (xx - 1)];
                }
                ptile[(pj0 + s) * 72 + ci_i] = f2bf(v);
            }
        }
        __syncthreads();
        {
            int p_i = t >> 2, c0 = (t & 3) * 16;
            int p = p0 + p_i;
            if (p < 1156) {
                u16* dst = xT + ((size_t)b * 1156 + p) * 512 + ci0 + c0;
                *(s16x8*)&dst[0] = *(const s16x8*)&ptile[p_i * 72 + c0];
                *(s16x8*)&dst[8] = *(const s16x8*)&ptile[p_i * 72 + c0 + 8];
            }
        }
    } else {                                // ---- xq cast
        int idx = (bid - 5888) * 256 + t;   // float4 groups, 2,097,152 total
        int row = idx >> 8, col4 = idx & 255;
        int b = row >> 9, c = row & 511;
        const float* src = (c < 256) ? (x1 + ((size_t)(b * 256 + c)) * 1024)
                                     : (x2 + ((size_t)(b * 256 + c - 256)) * 1024);
        float4 v = ((const float4*)src)[col4];
        u16x4 pk = {f2bf(v.x), f2bf(v.y), f2bf(v.z), f2bf(v.w)};
        *(u16x4*)&xq[(size_t)row * 1024 + col4 * 4] = pk;
    }
}

// ================================================================ SIM fused
// 256 blocks: b = bid&15, m0 = (bid>>4)*32. Each block: rows m0..m0+31, all 512 cols.
// sim = xq @ xq^T * scale + rm -> softmax -> bf16 transposed store to attnT[d][c]
__global__ __launch_bounds__(256) void sim_fused(const u16* __restrict__ xq,
                                                 const float* __restrict__ rm,
                                                 u16* __restrict__ attnT) {
    __shared__ __attribute__((aligned(16))) u16 As[32 * 64];    // 4 KB
    __shared__ __attribute__((aligned(16))) u16 Bs[512 * 64];   // 64 KB (reused as transpose tile)
    __shared__ float scr[256];
    const int t = threadIdx.x, w = t >> 6, l = t & 63;
    const int b = blockIdx.x & 15, m0 = (blockIdx.x >> 4) * 32;
    const u16* xb = xq + (size_t)b * 512 * 1024;

    const int rowg = w * 8 + (l >> 3);              // 0..31
    const int gi = (l & 7) ^ (rowg & 7);
    const u16* agp = xb + (size_t)(m0 + rowg) * 1024 + gi * 8;
    const u16* bgp = xb + (size_t)rowg * 1024 + gi * 8;
    u16* ald = &As[(w * 8) * 64];
    u16* bld = &Bs[(w * 8) * 64];

    f32x4 acc[2][8] = {};
    const int col = l & 15, hi = l >> 4;

    for (int kt = 0; kt < 16; ++kt) {
        const int ko = kt * 64;
        if (kt) __syncthreads();
        gload_lds16(agp + ko, ald);
#pragma unroll
        for (int i = 0; i < 16; ++i)
            gload_lds16(bgp + ko + i * 32768, bld + i * 2048);
        __syncthreads();
#pragma unroll
        for (int kk = 0; kk < 2; ++kk) {
            int gbase = kk * 4 + hi;
            s16x8 af[2], bf[8];
#pragma unroll
            for (int i = 0; i < 2; ++i) {
                int row = i * 16 + col;
                af[i] = *(const s16x8*)&As[row * 64 + ((gbase ^ (row & 7)) << 3)];
            }
#pragma unroll
            for (int j = 0; j < 8; ++j) {
                int n = w * 128 + j * 16 + col;
                bf[j] = *(const s16x8*)&Bs[n * 64 + ((gbase ^ (n & 7)) << 3)];
            }
#pragma unroll
            for (int i = 0; i < 2; ++i)
#pragma unroll
                for (int j = 0; j < 8; ++j)
                    acc[i][j] = __builtin_amdgcn_mfma_f32_16x16x32_bf16(af[i], bf[j], acc[i][j], 0, 0, 0);
        }
    }

    // ---- bias + softmax over full row (512) ----
    const float scale = 0.04419417382415922f;   // 512^-0.5
#pragma unroll
    for (int i = 0; i < 2; ++i)
#pragma unroll
        for (int j = 0; j < 8; ++j) {
            int n = w * 128 + j * 16 + col;
#pragma unroll
            for (int reg = 0; reg < 4; ++reg) {
                int rg = m0 + i * 16 + hi * 4 + reg;
                acc[i][j][reg] = acc[i][j][reg] * scale + rm[(size_t)rg * 512 + n];
            }
        }
    float mx[2][4];
#pragma unroll
    for (int i = 0; i < 2; ++i)
#pragma unroll
        for (int reg = 0; reg < 4; ++reg) {
            float m = acc[i][0][reg];
#pragma unroll
            for (int j = 1; j < 8; ++j) m = fmaxf(m, acc[i][j][reg]);
            m = fmaxf(m, __shfl_xor(m, 1, 64));
            m = fmaxf(m, __shfl_xor(m, 2, 64));
            m = fmaxf(m, __shfl_xor(m, 4, 64));
            m = fmaxf(m, __shfl_xor(m, 8, 64));
            mx[i][reg] = m;
        }
    if (col == 0) {
#pragma unroll
        for (int i = 0; i < 2; ++i)
#pragma unroll
            for (int reg = 0; reg < 4; ++reg)
                scr[w * 32 + i * 16 + hi * 4 + reg] = mx[i][reg];
    }
    __syncthreads();
    float sm[2][4];
#pragma unroll
    for (int i = 0; i < 2; ++i)
#pragma unroll
        for (int reg = 0; reg < 4; ++reg) {
            int rowl = i * 16 + hi * 4 + reg;
            float m = fmaxf(fmaxf(scr[rowl], scr[32 + rowl]),
                            fmaxf(scr[64 + rowl], scr[96 + rowl]));
            float s = 0.f;
#pragma unroll
            for (int j = 0; j < 8; ++j) {
                float e = __expf(acc[i][j][reg] - m);
                acc[i][j][reg] = e;
                s += e;
            }
            s += __shfl_xor(s, 1, 64);
            s += __shfl_xor(s, 2, 64);
            s += __shfl_xor(s, 4, 64);
            s += __shfl_xor(s, 8, 64);
            sm[i][reg] = s;
        }
    if (col == 0) {
#pragma unroll
        for (int i = 0; i < 2; ++i)
#pragma unroll
            for (int reg = 0; reg < 4; ++reg)
                scr[128 + w * 32 + i * 16 + hi * 4 + reg] = sm[i][reg];
    }
    __syncthreads();
#pragma unroll
    for (int i = 0; i < 2; ++i)
#pragma unroll
        for (int reg = 0; reg < 4; ++reg) {
            int rowl = i * 16 + hi * 4 + reg;
            float tot = scr[128 + rowl] + scr[160 + rowl] + scr[192 + rowl] + scr[224 + rowl];
            float inv = 1.f / tot;
#pragma unroll
            for (int j = 0; j < 8; ++j) acc[i][j][reg] *= inv;
        }
    __syncthreads();   // all Bs reads / scr reads done before tile overwrite
    // transpose tile [d(512)][c(32)] stride 40 in Bs
#pragma unroll
    for (int i = 0; i < 2; ++i)
#pragma unroll
        for (int j = 0; j < 8; ++j) {
            int d = w * 128 + j * 16 + col;
            int c = i * 16 + hi * 4;
            u16x4 pk = {f2bf(acc[i][j][0]), f2bf(acc[i][j][1]),
                        f2bf(acc[i][j][2]), f2bf(acc[i][j][3])};
            *(u16x4*)&Bs[d * 40 + c] = pk;
        }
    __syncthreads();
    {
        u16* aT = attnT + ((size_t)b * 512) * 512 + m0;
#pragma unroll
        for (int rep = 0; rep < 2; ++rep) {
            int d = t + rep * 256;
            u16* dst = aT + (size_t)d * 512;
            s16x8 v0 = *(const s16x8*)&Bs[d * 40];
            s16x8 v1 = *(const s16x8*)&Bs[d * 40 + 8];
            s16x8 v2 = *(const s16x8*)&Bs[d * 40 + 16];
            s16x8 v3 = *(const s16x8*)&Bs[d * 40 + 24];
            *(s16x8*)&dst[0] = v0;
            *(s16x8*)&dst[8] = v1;
            *(s16x8*)&dst[16] = v2;
            *(s16x8*)&dst[24] = v3;
        }
    }
}

// ================================================================ conv implicit GEMM (round-3 form)
__global__ __launch_bounds__(256) void conv_gemm(const u16* __restrict__ wA,
                                                 const u16* __restrict__ xT,
                                                 u16* __restrict__ vT) {
    __shared__ __attribute__((aligned(16))) u16 smem[128 * 128];
    u16* As = smem;               // 128 x 64
    u16* Bs = smem + 128 * 64;    // 128 x 64
    const int b = blockIdx.z, m0 = blockIdx.y * 128, n0 = blockIdx.x * 128;
    const int t = threadIdx.x, w = t >> 6, l = t & 63;
    const u16* xTb = xT + (size_t)b * 1156 * 512;

    int gi[4], pb[4];
    const u16* agp[4];
    u16 *ald[4], *bld[4];
#pragma unroll
    for (int i = 0; i < 4; ++i) {
        int rr = w * 8 + i * 32 + (l >> 3);
        gi[i] = (l & 7) ^ (rr & 7);
        agp[i] = wA + (size_t)(m0 + rr) * 4608 + gi[i] * 8;
        int n = n0 + rr;
        pb[i] = (n >> 5) * 34 + (n & 31);
        ald[i] = &As[(w * 8 + i * 32) * 64];
        bld[i] = &Bs[(w * 8 + i * 32) * 64];
    }

    f32x4 acc[4][4] = {};
    const int wm = (w >> 1) * 64, wn = (w & 1) * 64;

    for (int kt = 0; kt < 72; ++kt) {
        int r = kt >> 3, ci0k = (kt & 7) << 6;
        int rdiv3 = (r * 11) >> 5;
        int poff = rdiv3 * 34 + (r - rdiv3 * 3);
        int aofs = r * 512 + ci0k;
        if (kt) __syncthreads();
#pragma unroll
        for (int i = 0; i < 4; ++i) gload_lds16(agp[i] + aofs, ald[i]);
#pragma unroll
        for (int i = 0; i < 4; ++i)
            gload_lds16(xTb + (size_t)(pb[i] + poff) * 512 + ci0k + gi[i] * 8, bld[i]);
        __syncthreads();

#pragma unroll
        for (int kk = 0; kk < 2; ++kk) {
            int gbase = kk * 4 + (l >> 4);
            s16x8 af[4], bf[4];
#pragma unroll
            for (int i = 0; i < 4; ++i) {
                int row = wm + i * 16 + (l & 15);
                af[i] = *(const s16x8*)&As[row * 64 + ((gbase ^ (row & 7)) << 3)];
            }
#pragma unroll
            for (int j = 0; j < 4; ++j) {
                int row = wn + j * 16 + (l & 15);
                bf[j] = *(const s16x8*)&Bs[row * 64 + ((gbase ^ (row & 7)) << 3)];
            }
#pragma unroll
            for (int i = 0; i < 4; ++i)
#pragma unroll
                for (int j = 0; j < 4; ++j)
                    acc[i][j] = __builtin_amdgcn_mfma_f32_16x16x32_bf16(af[i], bf[j], acc[i][j], 0, 0, 0);
        }
    }

    __syncthreads();
    const int col = l & 15, r4 = (l >> 4) * 4;
#pragma unroll
    for (int i = 0; i < 4; ++i)
#pragma unroll
        for (int j = 0; j < 4; ++j) {
            int n_l = wn + j * 16 + col;
            int co_b = wm + i * 16 + r4;
            u16x4 pk = {f2bf(acc[i][j][0]), f2bf(acc[i][j][1]),
                        f2bf(acc[i][j][2]), f2bf(acc[i][j][3])};
            *(u16x4*)&smem[n_l * 128 + (co_b ^ ((n_l & 15) << 3))] = pk;
        }
    __syncthreads();
    u16* vTb = vT + (size_t)b * 1024 * 512;
    {
        int n_l = t >> 1;
#pragma unroll
        for (int rep = 0; rep < 8; ++rep) {
            int c0 = (((t & 1) + rep * 2) << 3);
            s16x8 v = *(const s16x8*)&smem[n_l * 128 + (c0 ^ ((n_l & 15) << 3))];
            *(s16x8*)&vTb[(size_t)(n0 + n_l) * 512 + m0 + c0] = v;
        }
    }
}

// ================================================================ generic bf16 MFMA NT GEMM
// MODE 1: bf16 out (wattn); MODE 2: f32 out (final)
template <int MODE>
__global__ __launch_bounds__(256) void gemm_nt(const u16* __restrict__ A, size_t sA,
                                               const u16* __restrict__ B, size_t sB,
                                               void* __restrict__ Cv, size_t sC,
                                               int K, int ldc) {
    __shared__ __attribute__((aligned(16))) u16 As[128 * 64];
    __shared__ __attribute__((aligned(16))) u16 Bs[128 * 64];
    const int b = blockIdx.z, m0 = blockIdx.y * 128, n0 = blockIdx.x * 128;
    const int t = threadIdx.x, w = t >> 6, l = t & 63;
    const u16* Ab = A + (size_t)b * sA;
    const u16* Bb = B + (size_t)b * sB;

    const u16 *agp[4], *bgp[4];
    u16 *ald[4], *bld[4];
#pragma unroll
    for (int i = 0; i < 4; ++i) {
        int rr = w * 8 + i * 32 + (l >> 3);
        int gi = (l & 7) ^ (rr & 7);
        agp[i] = Ab + (size_t)(m0 + rr) * K + gi * 8;
        bgp[i] = Bb + (size_t)(n0 + rr) * K + gi * 8;
        ald[i] = &As[(w * 8 + i * 32) * 64];
        bld[i] = &Bs[(w * 8 + i * 32) * 64];
    }

    f32x4 acc[4][4] = {};
    const int wm = (w >> 1) * 64, wn = (w & 1) * 64;
    const int nkt = K >> 6;
    for (int kt = 0; kt < nkt; ++kt) {
        int ko = kt << 6;
        if (kt) __syncthreads();
#pragma unroll
        for (int i = 0; i < 4; ++i) gload_lds16(agp[i] + ko, ald[i]);
#pragma unroll
        for (int i = 0; i < 4; ++i) gload_lds16(bgp[i] + ko, bld[i]);
        __syncthreads();
#pragma unroll
        for (int kk = 0; kk < 2; ++kk) {
            int gbase = kk * 4 + (l >> 4);
            s16x8 af[4], bf[4];
#pragma unroll
            for (int i = 0; i < 4; ++i) {
                int row = wm + i * 16 + (l & 15);
                af[i] = *(const s16x8*)&As[row * 64 + ((gbase ^ (row & 7)) << 3)];
            }
#pragma unroll
            for (int j = 0; j < 4; ++j) {
                int row = wn + j * 16 + (l & 15);
                bf[j] = *(const s16x8*)&Bs[row * 64 + ((gbase ^ (row & 7)) << 3)];
            }
#pragma unroll
            for (int i = 0; i < 4; ++i)
#pragma unroll
                for (int j = 0; j < 4; ++j)
                    acc[i][j] = __builtin_amdgcn_mfma_f32_16x16x32_bf16(af[i], bf[j], acc[i][j], 0, 0, 0);
        }
    }

    const int col = l & 15, r4 = (l >> 4) * 4;
#pragma unroll
    for (int i = 0; i < 4; ++i)
#pragma unroll
        for (int j = 0; j < 4; ++j)
#pragma unroll
            for (int reg = 0; reg < 4; ++reg) {
                int m = m0 + wm + i * 16 + r4 + reg;
                int n = n0 + wn + j * 16 + col;
                if (MODE == 1) {
                    u16* C = (u16*)Cv + (size_t)b * sC;
                    C[(size_t)m * ldc + n] = f2bf(acc[i][j][reg]);
                } else {
                    float* C = (float*)Cv + (size_t)b * sC;
                    C[(size_t)m * ldc + n] = acc[i][j][reg];
                }
            }
}

// ----------------------------------------------------------------
extern "C" void kernel_launch(void* const* d_in, const int* in_sizes, int n_in,
                              void* d_out, int out_size, void* d_ws, size_t ws_size,
                              hipStream_t stream) {
    (void)in_sizes; (void)n_in; (void)out_size; (void)ws_size;
    const float* x1 = (const float*)d_in[0];
    const float* x2 = (const float*)d_in[1];
    const float* gw = (const float*)d_in[2];
    const float* ww = (const float*)d_in[3];
    const float* w1 = (const float*)d_in[4];
    const float* w2 = (const float*)d_in[5];
    float* out = (float*)d_out;
    float* ws = (float*)d_ws;

    u16* xT    = (u16*)(ws + OFF_XT);
    u16* xq    = (u16*)(ws + OFF_VT);   // xq aliases vT (xq dead before conv writes vT)
    u16* vT    = (u16*)(ws + OFF_VT);
    u16* attnT = (u16*)(ws + OFF_ATTNT);
    u16* wattn = (u16*)(ws + OFF_WATTN);
    u16* wA    = (u16*)(ws + OFF_WA);
    float* rm  = ws + OFF_RM;
    u16* wwb   = (u16*)(ws + OFF_WWB);

    prep_kernel<<<14080, 256, 0, stream>>>(x1, x2, gw, ww, w1, w2, rm, wA, wwb, xT, xq);
    sim_fused<<<256, 256, 0, stream>>>(xq, rm, attnT);
    // wattn[b][o][d] = sum_c wwb[o][c] * attnT[b][d][c]  (bf16 out)
    gemm_nt<1><<<dim3(4, 2, 16), 256, 0, stream>>>(
        wwb, 0, attnT, (size_t)512 * 512, wattn, (size_t)256 * 512, 512, 512);
    conv_gemm<<<dim3(8, 4, 16), 256, 0, stream>>>(wA, xT, vT);
    // out[b][o][n] = sum_d wattn[b][o][d] * vT[b][n][d]  (f32 out)
    gemm_nt<2><<<dim3(8, 2, 16), 256, 0, stream>>>(
        wattn, (size_t)256 * 512, vT, (size_t)1024 * 512, out, (size_t)256 * 1024, 512, 1024);
}

// Round 6
// 232.044 us; speedup vs baseline: 1.5569x; 1.1395x over previous
//
#include <hip/hip_runtime.h>
#include <math.h>

typedef float f32x4 __attribute__((ext_vector_type(4)));
typedef short s16x8 __attribute__((ext_vector_type(8)));
typedef unsigned int u32;
typedef unsigned short u16;
typedef u16 u16x4 __attribute__((ext_vector_type(4)));

// ---------------- ws layout (float offsets), 50.1 MB peak ----------------
// XQ region reused: xq bf16 [16,512,1024] (prep..sim_gemm) -> attnT bf16
// [16,512,512] (softmax_t..gemm1) -> vT bf16 [16,1024,512] (conv..gemm2).
// SIMT region reused: simT bf16 [16,512,512] (sim_gemm..softmax_t) ->
// wattn bf16 [16,256,512] (gemm1..gemm2).
static constexpr size_t OFF_XT   = 0;          // bf16 [16,1156,512] = 4,734,976 fl
static constexpr size_t OFF_XQ   = 4734976;    // 4,194,304 fl
static constexpr size_t OFF_SIMT = 8929280;    // 2,097,152 fl
static constexpr size_t OFF_WA   = 11026432;   // bf16 [512,4608] = 1,179,648 fl
static constexpr size_t OFF_RM   = 12206080;   // f32 [512,512] = 262,144 fl
static constexpr size_t OFF_WWB  = 12468224;   // bf16 [256,512] = 65,536 fl
// end 12,533,760 fl = 50.1 MB

__device__ __forceinline__ u16 f2bf(float f) {
    u32 u = __float_as_uint(f);
    u32 r = (u + 0x7FFFu + ((u >> 16) & 1u)) >> 16;   // RNE
    return (u16)r;
}
__device__ __forceinline__ float bf2f(u16 v) {
    return __uint_as_float(((u32)v) << 16);
}

__device__ __forceinline__ void gload_lds16(const void* g, void* l) {
    __builtin_amdgcn_global_load_lds(
        (const u32 __attribute__((address_space(1)))*)(uintptr_t)g,
        (u32 __attribute__((address_space(3)))*)(uintptr_t)l, 16, 0, 0);
}

// ================================================================ PREP (grid-fused, coalesced)
// [0,512)      wA[co][r*512+ci] = bf16(g_w[co][ci][r]) via LDS (contiguous gw read)
// [512,2560)   x single-read: xq bf16 write + xT transposed write via LDS tile
// [2560,2576)  xT border rows zero
// [2576,3600)  rm = w1 @ w2^T
// [3600,3728)  wwb = bf16(w_w)
__global__ __launch_bounds__(256) void prep_kernel(const float* __restrict__ x1,
                                                   const float* __restrict__ x2,
                                                   const float* __restrict__ gw,
                                                   const float* __restrict__ ww,
                                                   const float* __restrict__ w1,
                                                   const float* __restrict__ w2,
                                                   float* __restrict__ rm,
                                                   u16* __restrict__ wA,
                                                   u16* __restrict__ wwb,
                                                   u16* __restrict__ xT,
                                                   u16* __restrict__ xq) {
    __shared__ __attribute__((aligned(16))) u32 shm[4608];   // 18.4 KB union
    const int t = threadIdx.x;
    const int bid = blockIdx.x;

    if (bid < 512) {                        // ---- gw permute-cast (co = bid)
        const int co = bid;
        const float* g = gw + (size_t)co * 4608;
        float* lf = (float*)shm;
#pragma unroll
        for (int i = 0; i < 18; ++i) lf[t + i * 256] = g[t + i * 256];
        __syncthreads();
        u16* dst = wA + (size_t)co * 4608;
#pragma unroll
        for (int i = 0; i < 18; ++i) {
            int k = t + i * 256;
            int r = k >> 9, ci = k & 511;
            dst[k] = f2bf(lf[ci * 9 + r]);
        }
    } else if (bid < 2560) {                // ---- x fused cast + transpose
        int xid = bid - 512;                // 2048 blocks
        int nt = xid & 15;                  // px tile (64 px = 2 image rows)
        int cit = (xid >> 4) & 7;           // 64-ch tile
        int b = xid >> 7;
        int n0 = nt * 64, ci0 = cit * 64;
        const float* src = (ci0 < 256) ? (x1 + ((size_t)(b * 256 + ci0)) * 1024)
                                       : (x2 + ((size_t)(b * 256 + ci0 - 256)) * 1024);
        u16* xqb = xq + ((size_t)(b * 512 + ci0)) * 1024;
        u16* lt = (u16*)shm;                // [64 px][65] bf16 tile
#pragma unroll
        for (int p4 = 0; p4 < 4; ++p4) {
            int ch = (t >> 4) + p4 * 16;
            int px = (t & 15) * 4;
            float4 v = *(const float4*)&src[(size_t)ch * 1024 + n0 + px];
            u16x4 pk = {f2bf(v.x), f2bf(v.y), f2bf(v.z), f2bf(v.w)};
            *(u16x4*)&xqb[(size_t)ch * 1024 + n0 + px] = pk;
            lt[(px + 0) * 65 + ch] = pk[0];
            lt[(px + 1) * 65 + ch] = pk[1];
            lt[(px + 2) * 65 + ch] = pk[2];
            lt[(px + 3) * 65 + ch] = pk[3];
        }
        __syncthreads();
        {
            int px_l = t >> 2, c16 = (t & 3) * 16;
            int n = n0 + px_l;
            int y = n >> 5, x = n & 31;
            int p = (y + 1) * 34 + (x + 1);
            u16* dst = xT + ((size_t)b * 1156 + p) * 512 + ci0 + c16;
            *(s16x8*)&dst[0] = *(const s16x8*)&lt[px_l * 65 + c16];
            *(s16x8*)&dst[8] = *(const s16x8*)&lt[px_l * 65 + c16 + 8];
        }
    } else if (bid < 2576) {                // ---- border zero (one block per b)
        int b = bid - 2560;
        u16* base = xT + (size_t)b * 1156 * 512;
        s16x8 z = {0, 0, 0, 0, 0, 0, 0, 0};
        for (int idx = t; idx < 132 * 64; idx += 256) {
            int row = idx >> 6, seg = idx & 63;
            int p;
            if (row < 34) p = row;
            else if (row < 68) p = 1122 + (row - 34);
            else if (row < 100) p = (row - 67) * 34;
            else p = (row - 99) * 34 + 33;
            *(s16x8*)&base[(size_t)p * 512 + seg * 8] = z;
        }
    } else if (bid < 3600) {                // ---- rm
        int idx = (bid - 2576) * 256 + t;
        int c = idx >> 9, d = idx & 511;
        float s = 0.f;
#pragma unroll
        for (int k = 0; k < 16; ++k) s = fmaf(w1[c * 16 + k], w2[d * 16 + k], s);
        rm[idx] = s;
    } else {                                // ---- wwb cast
        int idx = (bid - 3600) * 256 + t;
        float4 v = ((const float4*)ww)[idx];
        u16x4 pk = {f2bf(v.x), f2bf(v.y), f2bf(v.z), f2bf(v.w)};
        *(u16x4*)&wwb[(size_t)idx * 4] = pk;
    }
}

// ================================================================ SIM GEMM (conv-structure clone)
// simT[b][d][c] = bf16( (xq[c]·xq[d]) * scale + rm[c][d] )   (128x128 tile, BK=64)
__global__ __launch_bounds__(256) void sim_gemm(const u16* __restrict__ xq,
                                                const float* __restrict__ rm,
                                                u16* __restrict__ simT) {
    __shared__ __attribute__((aligned(16))) u16 smem[128 * 128];
    u16* As = smem;
    u16* Bs = smem + 128 * 64;
    const int b = blockIdx.z, m0 = blockIdx.y * 128, n0 = blockIdx.x * 128;
    const int t = threadIdx.x, w = t >> 6, l = t & 63;
    const u16* xb = xq + (size_t)b * 512 * 1024;

    const u16 *agp[4], *bgp[4];
    u16 *ald[4], *bld[4];
#pragma unroll
    for (int i = 0; i < 4; ++i) {
        int rr = w * 8 + i * 32 + (l >> 3);
        int gi = (l & 7) ^ (rr & 7);
        agp[i] = xb + (size_t)(m0 + rr) * 1024 + gi * 8;
        bgp[i] = xb + (size_t)(n0 + rr) * 1024 + gi * 8;
        ald[i] = &As[(w * 8 + i * 32) * 64];
        bld[i] = &Bs[(w * 8 + i * 32) * 64];
    }

    f32x4 acc[4][4] = {};
    const int wm = (w >> 1) * 64, wn = (w & 1) * 64;

    for (int kt = 0; kt < 16; ++kt) {
        int ko = kt << 6;
        if (kt) __syncthreads();
#pragma unroll
        for (int i = 0; i < 4; ++i) gload_lds16(agp[i] + ko, ald[i]);
#pragma unroll
        for (int i = 0; i < 4; ++i) gload_lds16(bgp[i] + ko, bld[i]);
        __syncthreads();
#pragma unroll
        for (int kk = 0; kk < 2; ++kk) {
            int gbase = kk * 4 + (l >> 4);
            s16x8 af[4], bf[4];
#pragma unroll
            for (int i = 0; i < 4; ++i) {
                int row = wm + i * 16 + (l & 15);
                af[i] = *(const s16x8*)&As[row * 64 + ((gbase ^ (row & 7)) << 3)];
            }
#pragma unroll
            for (int j = 0; j < 4; ++j) {
                int row = wn + j * 16 + (l & 15);
                bf[j] = *(const s16x8*)&Bs[row * 64 + ((gbase ^ (row & 7)) << 3)];
            }
#pragma unroll
            for (int i = 0; i < 4; ++i)
#pragma unroll
                for (int j = 0; j < 4; ++j)
                    acc[i][j] = __builtin_amdgcn_mfma_f32_16x16x32_bf16(af[i], bf[j], acc[i][j], 0, 0, 0);
        }
    }

    // epilogue: bias + transposed bf16 store (conv-style LDS transpose)
    __syncthreads();
    const int col = l & 15, r4 = (l >> 4) * 4;
    const float scale = 0.04419417382415922f;   // 512^-0.5
#pragma unroll
    for (int i = 0; i < 4; ++i)
#pragma unroll
        for (int j = 0; j < 4; ++j) {
            int n_l = wn + j * 16 + col;        // d within tile
            int m_b = wm + i * 16 + r4;         // c chunk base
            u16x4 pk;
#pragma unroll
            for (int reg = 0; reg < 4; ++reg) {
                float v = acc[i][j][reg] * scale
                        + rm[(size_t)(m0 + m_b + reg) * 512 + (n0 + n_l)];
                pk[reg] = f2bf(v);
            }
            *(u16x4*)&smem[n_l * 128 + (m_b ^ ((n_l & 15) << 3))] = pk;
        }
    __syncthreads();
    u16* sTb = simT + (size_t)b * 512 * 512;
    {
        int n_l = t >> 1;
#pragma unroll
        for (int rep = 0; rep < 8; ++rep) {
            int c0 = (((t & 1) + rep * 2) << 3);
            s16x8 v = *(const s16x8*)&smem[n_l * 128 + (c0 ^ ((n_l & 15) << 3))];
            *(s16x8*)&sTb[(size_t)(n0 + n_l) * 512 + m0 + c0] = v;
        }
    }
}

// ================================================================ column softmax over simT
// attnT[b][d][c] = exp(simT[d][c]) / sum_d exp(simT[d][c])   (no max: |sim|<~10, f32-safe)
// grid 256: b = bid>>4, c0 = (bid&15)*32. thread: c = c0+(t&31), d-group g = t>>5 (64 d each)
__global__ __launch_bounds__(256) void softmax_t(const u16* __restrict__ simT,
                                                 u16* __restrict__ attnT) {
    __shared__ float scr[256];
    const int t = threadIdx.x;
    const int b = blockIdx.x >> 4, c0 = (blockIdx.x & 15) * 32;
    const int cl = t & 31, g = t >> 5;
    const u16* sp = simT + (size_t)b * 512 * 512 + c0 + cl;
    u16* ap = attnT + (size_t)b * 512 * 512 + c0 + cl;

    float s = 0.f;
#pragma unroll 8
    for (int dd = 0; dd < 64; ++dd) {
        int d = g * 64 + dd;
        s += __expf(bf2f(sp[(size_t)d * 512]));
    }
    scr[t] = s;
    __syncthreads();
    float tot = 0.f;
#pragma unroll
    for (int k = 0; k < 8; ++k) tot += scr[k * 32 + cl];
    float inv = 1.f / tot;
#pragma unroll 8
    for (int dd = 0; dd < 64; ++dd) {
        int d = g * 64 + dd;
        float e = __expf(bf2f(sp[(size_t)d * 512])) * inv;
        ap[(size_t)d * 512] = f2bf(e);
    }
}

// ================================================================ conv implicit GEMM (unchanged)
__global__ __launch_bounds__(256) void conv_gemm(const u16* __restrict__ wA,
                                                 const u16* __restrict__ xT,
                                                 u16* __restrict__ vT) {
    __shared__ __attribute__((aligned(16))) u16 smem[128 * 128];
    u16* As = smem;
    u16* Bs = smem + 128 * 64;
    const int b = blockIdx.z, m0 = blockIdx.y * 128, n0 = blockIdx.x * 128;
    const int t = threadIdx.x, w = t >> 6, l = t & 63;
    const u16* xTb = xT + (size_t)b * 1156 * 512;

    int gi[4], pb[4];
    const u16* agp[4];
    u16 *ald[4], *bld[4];
#pragma unroll
    for (int i = 0; i < 4; ++i) {
        int rr = w * 8 + i * 32 + (l >> 3);
        gi[i] = (l & 7) ^ (rr & 7);
        agp[i] = wA + (size_t)(m0 + rr) * 4608 + gi[i] * 8;
        int n = n0 + rr;
        pb[i] = (n >> 5) * 34 + (n & 31);
        ald[i] = &As[(w * 8 + i * 32) * 64];
        bld[i] = &Bs[(w * 8 + i * 32) * 64];
    }

    f32x4 acc[4][4] = {};
    const int wm = (w >> 1) * 64, wn = (w & 1) * 64;

    for (int kt = 0; kt < 72; ++kt) {
        int r = kt >> 3, ci0k = (kt & 7) << 6;
        int rdiv3 = (r * 11) >> 5;
        int poff = rdiv3 * 34 + (r - rdiv3 * 3);
        int aofs = r * 512 + ci0k;
        if (kt) __syncthreads();
#pragma unroll
        for (int i = 0; i < 4; ++i) gload_lds16(agp[i] + aofs, ald[i]);
#pragma unroll
        for (int i = 0; i < 4; ++i)
            gload_lds16(xTb + (size_t)(pb[i] + poff) * 512 + ci0k + gi[i] * 8, bld[i]);
        __syncthreads();

#pragma unroll
        for (int kk = 0; kk < 2; ++kk) {
            int gbase = kk * 4 + (l >> 4);
            s16x8 af[4], bf[4];
#pragma unroll
            for (int i = 0; i < 4; ++i) {
                int row = wm + i * 16 + (l & 15);
                af[i] = *(const s16x8*)&As[row * 64 + ((gbase ^ (row & 7)) << 3)];
            }
#pragma unroll
            for (int j = 0; j < 4; ++j) {
                int row = wn + j * 16 + (l & 15);
                bf[j] = *(const s16x8*)&Bs[row * 64 + ((gbase ^ (row & 7)) << 3)];
            }
#pragma unroll
            for (int i = 0; i < 4; ++i)
#pragma unroll
                for (int j = 0; j < 4; ++j)
                    acc[i][j] = __builtin_amdgcn_mfma_f32_16x16x32_bf16(af[i], bf[j], acc[i][j], 0, 0, 0);
        }
    }

    __syncthreads();
    const int col = l & 15, r4 = (l >> 4) * 4;
#pragma unroll
    for (int i = 0; i < 4; ++i)
#pragma unroll
        for (int j = 0; j < 4; ++j) {
            int n_l = wn + j * 16 + col;
            int co_b = wm + i * 16 + r4;
            u16x4 pk = {f2bf(acc[i][j][0]), f2bf(acc[i][j][1]),
                        f2bf(acc[i][j][2]), f2bf(acc[i][j][3])};
            *(u16x4*)&smem[n_l * 128 + (co_b ^ ((n_l & 15) << 3))] = pk;
        }
    __syncthreads();
    u16* vTb = vT + (size_t)b * 1024 * 512;
    {
        int n_l = t >> 1;
#pragma unroll
        for (int rep = 0; rep < 8; ++rep) {
            int c0 = (((t & 1) + rep * 2) << 3);
            s16x8 v = *(const s16x8*)&smem[n_l * 128 + (c0 ^ ((n_l & 15) << 3))];
            *(s16x8*)&vTb[(size_t)(n0 + n_l) * 512 + m0 + c0] = v;
        }
    }
}

// ================================================================ generic bf16 MFMA NT GEMM
// MODE 1: bf16 out (wattn); MODE 2: f32 out (final)
template <int MODE>
__global__ __launch_bounds__(256) void gemm_nt(const u16* __restrict__ A, size_t sA,
                                               const u16* __restrict__ B, size_t sB,
                                               void* __restrict__ Cv, size_t sC,
                                               int K, int ldc) {
    __shared__ __attribute__((aligned(16))) u16 As[128 * 64];
    __shared__ __attribute__((aligned(16))) u16 Bs[128 * 64];
    const int b = blockIdx.z, m0 = blockIdx.y * 128, n0 = blockIdx.x * 128;
    const int t = threadIdx.x, w = t >> 6, l = t & 63;
    const u16* Ab = A + (size_t)b * sA;
    const u16* Bb = B + (size_t)b * sB;

    const u16 *agp[4], *bgp[4];
    u16 *ald[4], *bld[4];
#pragma unroll
    for (int i = 0; i < 4; ++i) {
        int rr = w * 8 + i * 32 + (l >> 3);
        int gi = (l & 7) ^ (rr & 7);
        agp[i] = Ab + (size_t)(m0 + rr) * K + gi * 8;
        bgp[i] = Bb + (size_t)(n0 + rr) * K + gi * 8;
        ald[i] = &As[(w * 8 + i * 32) * 64];
        bld[i] = &Bs[(w * 8 + i * 32) * 64];
    }

    f32x4 acc[4][4] = {};
    const int wm = (w >> 1) * 64, wn = (w & 1) * 64;
    const int nkt = K >> 6;
    for (int kt = 0; kt < nkt; ++kt) {
        int ko = kt << 6;
        if (kt) __syncthreads();
#pragma unroll
        for (int i = 0; i < 4; ++i) gload_lds16(agp[i] + ko, ald[i]);
#pragma unroll
        for (int i = 0; i < 4; ++i) gload_lds16(bgp[i] + ko, bld[i]);
        __syncthreads();
#pragma unroll
        for (int kk = 0; kk < 2; ++kk) {
            int gbase = kk * 4 + (l >> 4);
            s16x8 af[4], bf[4];
#pragma unroll
            for (int i = 0; i < 4; ++i) {
                int row = wm + i * 16 + (l & 15);
                af[i] = *(const s16x8*)&As[row * 64 + ((gbase ^ (row & 7)) << 3)];
            }
#pragma unroll
            for (int j = 0; j < 4; ++j) {
                int row = wn + j * 16 + (l & 15);
                bf[j] = *(const s16x8*)&Bs[row * 64 + ((gbase ^ (row & 7)) << 3)];
            }
#pragma unroll
            for (int i = 0; i < 4; ++i)
#pragma unroll
                for (int j = 0; j < 4; ++j)
                    acc[i][j] = __builtin_amdgcn_mfma_f32_16x16x32_bf16(af[i], bf[j], acc[i][j], 0, 0, 0);
        }
    }

    const int col = l & 15, r4 = (l >> 4) * 4;
#pragma unroll
    for (int i = 0; i < 4; ++i)
#pragma unroll
        for (int j = 0; j < 4; ++j)
#pragma unroll
            for (int reg = 0; reg < 4; ++reg) {
                int m = m0 + wm + i * 16 + r4 + reg;
                int n = n0 + wn + j * 16 + col;
                if (MODE == 1) {
                    u16* C = (u16*)Cv + (size_t)b * sC;
                    C[(size_t)m * ldc + n] = f2bf(acc[i][j][reg]);
                } else {
                    float* C = (float*)Cv + (size_t)b * sC;
                    C[(size_t)m * ldc + n] = acc[i][j][reg];
                }
            }
}

// ----------------------------------------------------------------
extern "C" void kernel_launch(void* const* d_in, const int* in_sizes, int n_in,
                              void* d_out, int out_size, void* d_ws, size_t ws_size,
                              hipStream_t stream) {
    (void)in_sizes; (void)n_in; (void)out_size; (void)ws_size;
    const float* x1 = (const float*)d_in[0];
    const float* x2 = (const float*)d_in[1];
    const float* gw = (const float*)d_in[2];
    const float* ww = (const float*)d_in[3];
    const float* w1 = (const float*)d_in[4];
    const float* w2 = (const float*)d_in[5];
    float* out = (float*)d_out;
    float* ws = (float*)d_ws;

    u16* xT    = (u16*)(ws + OFF_XT);
    u16* xq    = (u16*)(ws + OFF_XQ);
    u16* attnT = (u16*)(ws + OFF_XQ);     // after xq dies
    u16* vT    = (u16*)(ws + OFF_XQ);     // after attnT dies
    u16* simT  = (u16*)(ws + OFF_SIMT);
    u16* wattn = (u16*)(ws + OFF_SIMT);   // after simT dies
    u16* wA    = (u16*)(ws + OFF_WA);
    float* rm  = ws + OFF_RM;
    u16* wwb   = (u16*)(ws + OFF_WWB);

    prep_kernel<<<3728, 256, 0, stream>>>(x1, x2, gw, ww, w1, w2, rm, wA, wwb, xT, xq);
    sim_gemm<<<dim3(4, 4, 16), 256, 0, stream>>>(xq, rm, simT);
    softmax_t<<<256, 256, 0, stream>>>(simT, attnT);
    // wattn[b][o][d] = sum_c wwb[o][c] * attnT[b][d][c]  (bf16 out)
    gemm_nt<1><<<dim3(4, 2, 16), 256, 0, stream>>>(
        wwb, 0, attnT, (size_t)512 * 512, wattn, (size_t)256 * 512, 512, 512);
    conv_gemm<<<dim3(8, 4, 16), 256, 0, stream>>>(wA, xT, vT);
    // out[b][o][n] = sum_d wattn[b][o][d] * vT[b][n][d]  (f32 out)
    gemm_nt<2><<<dim3(8, 2, 16), 256, 0, stream>>>(
        wattn, (size_t)256 * 512, vT, (size_t)1024 * 512, out, (size_t)256 * 1024, 512, 1024);
}